// Round 16
// baseline (126.779 us; speedup 1.0000x reference)
//
#include <hip/hip_runtime.h>
#include <hip/hip_bf16.h>

// out[b,h,w,dy*9+dx] = leaky_relu( mean_c( prv[b,h,w,c] * nxt[b,h+dy-4,w+dx-4,c] ), 0.1 )
// R16: global_load_lds-direct B staging (f32 in LDS, cvt on read), double buffer,
// one vmcnt(0)+barrier per phase AFTER compute. A in registers (wave-private row).
// LDS layout: per (granule g=4ch, chunk c=64px) 1KB linear region at g*GRB + c*1024
// (gload dest is wave-uniform base + lane*16 -> must be linear; +16B/granule stagger
// keeps ds_read_b128 ~2-way). OOB lanes read a zeroed d_ws page (hipMemsetAsync).

#define B_ 8
#define H_ 128
#define W_ 128
#define C_ 192
#define ND 9
#define NDISP 81
#define HT 16           // tile rows
#define WT 16           // tile cols
#define KS 32           // channels per phase
#define NK 6            // 192/32
#define BCOLS 24        // staged nxt cols (rows = 24 too)
#define GRB 9232        // granule region block: 9*1024 + 16 stagger (16B-aligned)
#define BUFB (8 * GRB)  // 73856 B per buffer

typedef short short8 __attribute__((ext_vector_type(8)));
typedef short short4_t __attribute__((ext_vector_type(4)));
typedef float f32x4 __attribute__((ext_vector_type(4)));

static __device__ __forceinline__ short bf1(float f) {
    __hip_bfloat16 h = __float2bfloat16(f);   // pairs fuse to v_cvt_pk_bf16_f32
    return __builtin_bit_cast(short, h);
}

static __device__ __forceinline__ short4_t cvt4(float4 v) {
    short4_t r;
    r[0] = bf1(v.x); r[1] = bf1(v.y); r[2] = bf1(v.z); r[3] = bf1(v.w);
    return r;
}

static __device__ __forceinline__ short8 cat(short4_t u, short4_t v) {
    return __builtin_shufflevector(u, v, 0, 1, 2, 3, 4, 5, 6, 7);
}

// async global->LDS, 16B per lane; dest = wave-uniform base (+lane*16 by HW)
static __device__ __forceinline__ void gload16(const float* g, char* l) {
    __builtin_amdgcn_global_load_lds(
        (const __attribute__((address_space(1))) void*)g,
        (__attribute__((address_space(3))) void*)l,
        16, 0, 0);
}

// LDS byte offset of granule g, pixel px (f32x4 slot)
static __device__ __forceinline__ int lbyte(int g, int px) {
    return g * GRB + ((px >> 6) << 10) + ((px & 63) << 4);
}

__global__ __launch_bounds__(1024, 4)
void cv_mfma(const float* __restrict__ prv, const float* __restrict__ nxt,
             const float* __restrict__ zp,   // >=1KB of zeros (d_ws)
             float* __restrict__ out) {
    __shared__ char sm[2][BUFB] __attribute__((aligned(16)));   // 147.7 KB
    char* smb = &sm[0][0];

    const int tid = threadIdx.x;
    const int w0 = blockIdx.x * WT;
    const int h0 = blockIdx.y * HT;
    const int b  = blockIdx.z;

    const int lane = tid & 63;
    const int wid  = tid >> 6;      // 0..15: wave owns output row h0+wid
    const int lq = lane & 15;
    const int lc = lane >> 4;

    // ---- B stage-load descriptors: 72 one-KB loads (g=0..7, c=0..8), wave w owns
    // i = w, w+16, ... ; per-lane src = pixel c*64+lane, granule g (4ch), or zero page.
    const int nld = (wid < 8) ? 5 : 4;
    const float* bptr[5];
    int ldst[5];
#pragma unroll
    for (int j = 0; j < 5; ++j) {
        bptr[j] = zp; ldst[j] = 0;
        const int i = wid + 16 * j;
        if (i < 72) {
            const int g = i / 9;
            const int c = i - 9 * g;
            const int px = c * 64 + lane;
            const int row = px / BCOLS;
            const int col = px - row * BCOLS;
            const int gh = h0 - 4 + row;
            const int gw = w0 - 4 + col;
            const bool inb = ((unsigned)gh < (unsigned)H_) && ((unsigned)gw < (unsigned)W_);
            bptr[j] = inb ? (nxt + ((b * H_ + gh) * W_ + gw) * C_ + g * 4) : zp;
            ldst[j] = g * GRB + c * 1024;
        }
    }

    // ---- A: wave-private row; thread covers pixel (wid, lq), ch lc*8 (+KS per phase)
    const int aoff = ((b * H_ + h0 + wid) * W_ + w0 + lq) * C_ + lc * 8;

#define STAGE(KK, BUFN)                                                     \
    {                                                                       \
        _Pragma("unroll")                                                   \
        for (int j = 0; j < 5; ++j)                                         \
            if (j < nld) gload16(bptr[j] + (KK) * KS, (BUFN) + ldst[j]);    \
    }

    // ---- prologue: B(0) into buffer 0; A(0) into regs
    STAGE(0, smb)
    float4 xa0 = *(const float4*)(prv + aoff);
    float4 xa1 = *(const float4*)(prv + aoff + 4);
    asm volatile("s_waitcnt vmcnt(0)\n\ts_barrier" ::: "memory");

    f32x4 acc[ND][2];
#pragma unroll
    for (int d = 0; d < ND; ++d) {
        acc[d][0] = (f32x4){0.f, 0.f, 0.f, 0.f};
        acc[d][1] = (f32x4){0.f, 0.f, 0.f, 0.f};
    }

    for (int it = 0; it < NK; ++it) {
        char* bufc = smb + (it & 1) * BUFB;          // read buffer: holds B(it)
        char* bufn = smb + ((it + 1) & 1) * BUFB;    // free: all waves passed last
                                                     // barrier => done reading it-1
        const short8 af = cat(cvt4(xa0), cvt4(xa1));  // A(it) frag

        if (it + 1 < NK) {
            STAGE(it + 1, bufn)                       // async; drains after compute
            const int co = (it + 1) * KS;
            xa0 = *(const float4*)(prv + aoff + co);
            xa1 = *(const float4*)(prv + aoff + co + 4);
        }

        // ---- compute: 9 dy x 2 col-tiles; B frags read f32 from LDS, cvt on use
#pragma unroll
        for (int dy = 0; dy < ND; ++dy) {
            const int p0 = (wid + dy) * BCOLS + lq;
            const float4 f00 = *(const float4*)(bufc + lbyte(2 * lc, p0));
            const float4 f01 = *(const float4*)(bufc + lbyte(2 * lc + 1, p0));
            const float4 f10 = *(const float4*)(bufc + lbyte(2 * lc, p0 + 8));
            const float4 f11 = *(const float4*)(bufc + lbyte(2 * lc + 1, p0 + 8));
            const short8 b0 = cat(cvt4(f00), cvt4(f01));
            const short8 b1 = cat(cvt4(f10), cvt4(f11));
            acc[dy][0] = __builtin_amdgcn_mfma_f32_16x16x32_bf16(af, b0, acc[dy][0], 0, 0, 0);
            acc[dy][1] = __builtin_amdgcn_mfma_f32_16x16x32_bf16(af, b1, acc[dy][1], 0, 0, 0);
        }

        // drain this phase's async loads (latency covered by compute), then sync
        asm volatile("s_waitcnt vmcnt(0)\n\ts_barrier" ::: "memory");
    }
#undef STAGE

    // ---- epilogue (R5/R12/R13-verified): D col=lane&15 (q), D row=4*lc+rg (rD=w-pos).
    // rows rD<8 from tile0 (dx=q-rD), rD>=8 from tile1 (dx=q-rD+8); exclusive+complete.
    const float inv = 1.0f / (float)C_;
    const int h = h0 + wid;
    if (lc < 2) {
#pragma unroll
        for (int rg = 0; rg < 4; ++rg) {
            const int r = 4 * lc + rg;
            const int dx = lq - r;
            if (dx >= 0 && dx <= 8) {
                float* o = out + (size_t)((b * H_ + h) * W_ + w0 + r) * NDISP + dx;
#pragma unroll
                for (int dy = 0; dy < ND; ++dy) {
                    const float v = acc[dy][0][rg] * inv;
                    o[dy * ND] = v >= 0.f ? v : 0.1f * v;
                }
            }
        }
    } else {
#pragma unroll
        for (int rg = 0; rg < 4; ++rg) {
            const int r = 4 * lc + rg;       // 8..15
            const int dx = lq - r + 8;
            if (dx >= 0 && dx <= 8) {
                float* o = out + (size_t)((b * H_ + h) * W_ + w0 + r) * NDISP + dx;
#pragma unroll
                for (int dy = 0; dy < ND; ++dy) {
                    const float v = acc[dy][1][rg] * inv;
                    o[dy * ND] = v >= 0.f ? v : 0.1f * v;
                }
            }
        }
    }
}

extern "C" void kernel_launch(void* const* d_in, const int* in_sizes, int n_in,
                              void* d_out, int out_size, void* d_ws, size_t ws_size,
                              hipStream_t stream) {
    const float* prv = (const float*)d_in[0];
    const float* nxt = (const float*)d_in[1];
    float* out = (float*)d_out;

    // zero page for OOB staging lanes (stream-ordered; graph-capture safe)
    hipMemsetAsync(d_ws, 0, 1024, stream);

    dim3 grid(W_ / WT, H_ / HT, B_);   // (8, 8, 8) = 512 blocks x 1024 threads
    cv_mfma<<<grid, 1024, 0, stream>>>(prv, nxt, (const float*)d_ws, out);
}

// Round 17
// 121.123 us; speedup vs baseline: 1.0467x; 1.0467x over previous
//
#include <hip/hip_runtime.h>
#include <hip/hip_bf16.h>

// out[b,h,w,dy*9+dx] = leaky_relu( mean_c( prv[b,h,w,c] * nxt[b,h+dy-4,w+dx-4,c] ), 0.1 )
// R17: 16x16 tile; B staged by global_load_lds DMA into f32 scratch (linear 1KB
// regions), converted ONCE per element by a cvt-pass into R15's verified bf16
// granule layout, computed from bf16 (R15 fast path). Two barriers/phase; DMA for
// phase it+2 issued at end of phase it -> a full compute phase of latency cover,
// with zero B register staging (acc 72 + ~55 VGPR fits 4 waves/SIMD).

#define B_ 8
#define H_ 128
#define W_ 128
#define C_ 192
#define ND 9
#define NDISP 81
#define HT 16           // tile rows
#define WT 16           // tile cols
#define KS 32           // channels per phase
#define NK 6            // 192/32
#define BCOLS 24        // staged nxt cols (rows = 24)
#define BPIX 576
#define NGR 8           // 4-ch granules per phase
#define SCRB (72 * 1024)        // f32 scratch: 72 x 1KB gload regions
#define BSTR 577                // odd 8B-slot stride in bf16 layout
#define BUFB (NGR * BSTR * 8)   // 36928 B per bf16 buffer
#define CVTN 4608               // granule-elements per phase (8 * 576)

typedef short short8 __attribute__((ext_vector_type(8)));
typedef short short4_t __attribute__((ext_vector_type(4)));
typedef float f32x4 __attribute__((ext_vector_type(4)));

static __device__ __forceinline__ short bf1(float f) {
    __hip_bfloat16 h = __float2bfloat16(f);
    return __builtin_bit_cast(short, h);
}

static __device__ __forceinline__ short4_t cvt4(float4 v) {
    short4_t r;
    r[0] = bf1(v.x); r[1] = bf1(v.y); r[2] = bf1(v.z); r[3] = bf1(v.w);
    return r;
}

static __device__ __forceinline__ short8 cat(short4_t u, short4_t v) {
    return __builtin_shufflevector(u, v, 0, 1, 2, 3, 4, 5, 6, 7);
}

// async global->LDS, 16B/lane; dest = wave-uniform base (+lane*16 by HW)
static __device__ __forceinline__ void gload16(const float* g, char* l) {
    __builtin_amdgcn_global_load_lds(
        (const __attribute__((address_space(1))) void*)g,
        (__attribute__((address_space(3))) void*)l,
        16, 0, 0);
}

__global__ __launch_bounds__(1024, 4)
void cv_mfma(const float* __restrict__ prv, const float* __restrict__ nxt,
             const float* __restrict__ zp,   // >=1KB zeros (d_ws)
             float* __restrict__ out) {
    __shared__ char sm[SCRB + 2 * BUFB] __attribute__((aligned(16)));   // 147.6 KB
    char* scratch = sm;
    char* lay = sm + SCRB;

    const int tid = threadIdx.x;
    const int w0 = blockIdx.x * WT;
    const int h0 = blockIdx.y * HT;
    const int b  = blockIdx.z;

    const int lane = tid & 63;
    const int wid  = tid >> 6;      // 0..15: wave owns output row h0+wid
    const int lq = lane & 15;
    const int lc = lane >> 4;

    // ---- DMA descriptors: 72 x 1KB loads; wave w owns i = w, w+16, ...
    const int nld = (wid < 8) ? 5 : 4;
    const float* bptr[5];
    int ldst[5];
#pragma unroll
    for (int j = 0; j < 5; ++j) {
        bptr[j] = zp; ldst[j] = 0;
        const int i = wid + 16 * j;
        if (i < 72) {
            const int g = i / 9;           // ch granule 0..7 (4 ch)
            const int c = i - 9 * g;       // 64-px chunk 0..8
            const int px = c * 64 + lane;
            const int row = px / BCOLS;
            const int col = px - row * BCOLS;
            const int gh = h0 - 4 + row;
            const int gw = w0 - 4 + col;
            const bool inb = ((unsigned)gh < (unsigned)H_) && ((unsigned)gw < (unsigned)W_);
            bptr[j] = inb ? (nxt + ((b * H_ + gh) * W_ + gw) * C_ + g * 4) : zp;
            ldst[j] = (g * 9 + c) * 1024;
        }
    }

    // ---- cvt-pass descriptors: element i = tid + 1024k; g=i/576, px=i%576
    //      read scratch f32x4 at (g*9 + px/64)*1024 + (px%64)*16
    //      write bf16 granule slot g*BSTR + px (8B units)
    int cvs[5], cvd[5];
#pragma unroll
    for (int k = 0; k < 5; ++k) {
        const int i = tid + 1024 * k;
        cvs[k] = 0; cvd[k] = 0;
        if (i < CVTN) {
            const int g = i / BPIX;
            const int px = i - g * BPIX;
            cvs[k] = (g * 9 + (px >> 6)) * 1024 + ((px & 63) << 4);
            cvd[k] = (g * BSTR + px) * 8;
        }
    }
    const int ncv = (tid < 512) ? 5 : 4;

    // ---- A: wave-private row
    const int aoff = ((b * H_ + h0 + wid) * W_ + w0 + lq) * C_ + lc * 8;

#define STAGE(KK)                                                           \
    {                                                                       \
        _Pragma("unroll")                                                   \
        for (int j = 0; j < 5; ++j)                                         \
            if (j < nld) gload16(bptr[j] + (KK) * KS, scratch + ldst[j]);   \
    }
#define CVTPASS(BUF)                                                        \
    {                                                                       \
        _Pragma("unroll")                                                   \
        for (int k = 0; k < 5; ++k)                                         \
            if (k < ncv) {                                                  \
                const float4 v = *(const float4*)(scratch + cvs[k]);        \
                *(short4_t*)((BUF) + cvd[k]) = cvt4(v);                     \
            }                                                               \
    }

    // ---- prologue: B(0) -> scratch -> buf0; B(1) -> scratch; A(0)
    STAGE(0)
    float4 xa0 = *(const float4*)(prv + aoff);
    float4 xa1 = *(const float4*)(prv + aoff + 4);
    asm volatile("s_waitcnt vmcnt(0)\n\ts_barrier" ::: "memory");
    CVTPASS(lay)
    asm volatile("s_waitcnt lgkmcnt(0)\n\ts_barrier" ::: "memory");
    STAGE(1)

    f32x4 acc[ND][2];
#pragma unroll
    for (int d = 0; d < ND; ++d) {
        acc[d][0] = (f32x4){0.f, 0.f, 0.f, 0.f};
        acc[d][1] = (f32x4){0.f, 0.f, 0.f, 0.f};
    }

    for (int it = 0; it < NK; ++it) {
        char* bufc = lay + (it & 1) * BUFB;
        char* bufn = lay + ((it + 1) & 1) * BUFB;

        // ---- compute B(it): R15-verified bf16 path (gloads(it+1) fly underneath)
        const short8 af = cat(cvt4(xa0), cvt4(xa1));
#pragma unroll
        for (int dy = 0; dy < ND; ++dy) {
            const int pB = (wid + dy) * BCOLS + lq;
            const short8 b0 = cat(*(const short4_t*)(bufc + (2 * lc * BSTR + pB) * 8),
                                  *(const short4_t*)(bufc + ((2 * lc + 1) * BSTR + pB) * 8));
            const short8 b1 = cat(*(const short4_t*)(bufc + (2 * lc * BSTR + pB + 8) * 8),
                                  *(const short4_t*)(bufc + ((2 * lc + 1) * BSTR + pB + 8) * 8));
            acc[dy][0] = __builtin_amdgcn_mfma_f32_16x16x32_bf16(af, b0, acc[dy][0], 0, 0, 0);
            acc[dy][1] = __builtin_amdgcn_mfma_f32_16x16x32_bf16(af, b1, acc[dy][1], 0, 0, 0);
        }

        if (it + 1 < NK) {
            // own DMAs drained, then publish to all waves
            asm volatile("s_waitcnt vmcnt(0)\n\ts_barrier" ::: "memory");
            CVTPASS(bufn)                         // once-per-element f32->bf16
            asm volatile("s_waitcnt lgkmcnt(0)\n\ts_barrier" ::: "memory");
            if (it + 2 < NK) STAGE(it + 2)        // DMA under next compute
            const int co = (it + 1) * KS;
            xa0 = *(const float4*)(prv + aoff + co);
            xa1 = *(const float4*)(prv + aoff + co + 4);
        }
    }
#undef STAGE
#undef CVTPASS

    // ---- epilogue (R5/R12/R13-verified): D col=lane&15 (q), D row=4*lc+rg (rD=w-pos).
    // rows rD<8 from tile0 (dx=q-rD), rD>=8 from tile1 (dx=q-rD+8); exclusive+complete.
    const float inv = 1.0f / (float)C_;
    const int h = h0 + wid;
    if (lc < 2) {
#pragma unroll
        for (int rg = 0; rg < 4; ++rg) {
            const int r = 4 * lc + rg;
            const int dx = lq - r;
            if (dx >= 0 && dx <= 8) {
                float* o = out + (size_t)((b * H_ + h) * W_ + w0 + r) * NDISP + dx;
#pragma unroll
                for (int dy = 0; dy < ND; ++dy) {
                    const float v = acc[dy][0][rg] * inv;
                    o[dy * ND] = v >= 0.f ? v : 0.1f * v;
                }
            }
        }
    } else {
#pragma unroll
        for (int rg = 0; rg < 4; ++rg) {
            const int r = 4 * lc + rg;       // 8..15
            const int dx = lq - r + 8;
            if (dx >= 0 && dx <= 8) {
                float* o = out + (size_t)((b * H_ + h) * W_ + w0 + r) * NDISP + dx;
#pragma unroll
                for (int dy = 0; dy < ND; ++dy) {
                    const float v = acc[dy][1][rg] * inv;
                    o[dy * ND] = v >= 0.f ? v : 0.1f * v;
                }
            }
        }
    }
}

extern "C" void kernel_launch(void* const* d_in, const int* in_sizes, int n_in,
                              void* d_out, int out_size, void* d_ws, size_t ws_size,
                              hipStream_t stream) {
    const float* prv = (const float*)d_in[0];
    const float* nxt = (const float*)d_in[1];
    float* out = (float*)d_out;

    // zero page for OOB DMA lanes (stream-ordered; graph-capture safe, proven R16)
    hipMemsetAsync(d_ws, 0, 1024, stream);

    dim3 grid(W_ / WT, H_ / HT, B_);   // (8, 8, 8) = 512 blocks x 1024 threads
    cv_mfma<<<grid, 1024, 0, stream>>>(prv, nxt, (const float*)d_ws, out);
}